// Round 5
// baseline (1711.847 us; speedup 1.0000x reference)
//
#include <hip/hip_runtime.h>

#define NADDR 400000
#define NTX   400000
#define NEDGE 1500000
#define FIN   64
#define HID   32
#define NB    1563        // buckets per node type; 256 nodes per bucket
#define PADROW 34         // 32 feats + deg + pad (bank spread)

static inline int cdiv_host(long a, int b) { return (int)((a + b - 1) / b); }

// ================= bucketed edge build ======================================

// ---- per-bucket histogram (LDS-aggregated), both edge types ----
__global__ void k_hist(const int* __restrict__ at_dst, const int* __restrict__ ta_dst,
                       int* __restrict__ bcnt /*[2*NB]*/, int GH) {
    __shared__ int h[NB];
    bool wh = blockIdx.x >= GH;
    int blk = blockIdx.x - (wh ? GH : 0);
    const int* dst = wh ? ta_dst : at_dst;
    for (int i = threadIdx.x; i < NB; i += 256) h[i] = 0;
    __syncthreads();
    for (long e = (long)blk * 256 + threadIdx.x; e < NEDGE; e += (long)GH * 256)
        atomicAdd(&h[dst[e] >> 8], 1);
    __syncthreads();
    int* g = bcnt + (wh ? NB : 0);
    for (int i = threadIdx.x; i < NB; i += 256) {
        int v = h[i];
        if (v) atomicAdd(&g[i], v);
    }
}

// ---- 2 blocks: exclusive scan of each type's NB bucket counts ----
__global__ void k_scan_nb(const int* __restrict__ bcnt, int* __restrict__ bbase,
                          int* __restrict__ gcur) {
    __shared__ int sm[256];
    __shared__ int carry;
    int w = blockIdx.x;
    int t = threadIdx.x;
    if (t == 0) carry = 0;
    __syncthreads();
    for (int base = 0; base < NB; base += 256) {
        int i = base + t;
        int v = (i < NB) ? bcnt[w * NB + i] : 0;
        sm[t] = v;
        __syncthreads();
        for (int off = 1; off < 256; off <<= 1) {
            int x = (t >= off) ? sm[t - off] : 0;
            __syncthreads();
            sm[t] += x;
            __syncthreads();
        }
        int excl = sm[t] - v + carry;
        if (i < NB) { bbase[w * (NB + 1) + i] = excl; gcur[w * NB + i] = excl; }
        int tot = sm[255];
        __syncthreads();
        if (t == 0) carry += tot;
        __syncthreads();
    }
    if (t == 0) bbase[w * (NB + 1) + NB] = NEDGE;
}

// ---- distribute edges into bucket regions, packed (src<<8)|dst_local ----
__global__ void k_dist(const int* __restrict__ ei_at, const int* __restrict__ ei_ta,
                       int* __restrict__ gcur, unsigned* __restrict__ eb_at,
                       unsigned* __restrict__ eb_ta, int GD) {
    __shared__ int h[NB];
    __shared__ int bs[NB];
    bool wh = blockIdx.x >= GD;
    int blk = blockIdx.x - (wh ? GD : 0);
    const int* ei = wh ? ei_ta : ei_at;
    unsigned* eb = wh ? eb_ta : eb_at;
    for (int i = threadIdx.x; i < NB; i += 256) h[i] = 0;
    __syncthreads();
    long e0 = (long)blk * 256 + threadIdx.x;
    long stride = (long)GD * 256;
    for (long e = e0; e < NEDGE; e += stride)
        atomicAdd(&h[ei[NEDGE + e] >> 8], 1);
    __syncthreads();
    int* gc = gcur + (wh ? NB : 0);
    for (int i = threadIdx.x; i < NB; i += 256) {
        int c = h[i];
        bs[i] = c ? atomicAdd(&gc[i], c) : 0;
        h[i] = 0;
    }
    __syncthreads();
    for (long e = e0; e < NEDGE; e += stride) {
        int d = ei[NEDGE + e];
        int s = ei[e];
        int b = d >> 8;
        int r = atomicAdd(&h[b], 1);
        eb[bs[b] + r] = ((unsigned)s << 8) | (unsigned)(d & 255);
    }
}

// ================= dense pre-transform (layer 1 only) =======================

template<int F>
__global__ void k_linear(const float* __restrict__ x, const float* __restrict__ w,
                         float* __restrict__ y, int n) {
    int i = blockIdx.x * 256 + threadIdx.x;
    if (i >= n) return;
    const float4* xr = (const float4*)(x + (size_t)i * F);
    float acc[HID];
#pragma unroll
    for (int j = 0; j < HID; ++j) acc[j] = 0.0f;
#pragma unroll
    for (int k4 = 0; k4 < F / 4; ++k4) {
        float4 xv = xr[k4];
        const float* wr = w + k4 * 4 * HID;
#pragma unroll
        for (int j = 0; j < HID; ++j) acc[j] = __builtin_fmaf(xv.x, wr[j], acc[j]);
#pragma unroll
        for (int j = 0; j < HID; ++j) acc[j] = __builtin_fmaf(xv.y, wr[HID + j], acc[j]);
#pragma unroll
        for (int j = 0; j < HID; ++j) acc[j] = __builtin_fmaf(xv.z, wr[2 * HID + j], acc[j]);
#pragma unroll
        for (int j = 0; j < HID; ++j) acc[j] = __builtin_fmaf(xv.w, wr[3 * HID + j], acc[j]);
    }
    float* yr = y + (size_t)i * HID;
#pragma unroll
    for (int j = 0; j < HID; j += 4) {
        float4 o = make_float4(acc[j], acc[j + 1], acc[j + 2], acc[j + 3]);
        *(float4*)(yr + j) = o;
    }
}

// ================= fused edge-centric SAGE layer ============================
// One block per 256-dst-node bucket. Phase 1: stream the bucket's packed
// edges, gather src rows (float4 x 8 lanes), accumulate into LDS via native
// ds_add_f32 atomics (+degree). Phase 2: thread t = node t does the dense
// epilogue fully in registers: relu(mean@Wl + self@Wr + b) [PRE skips Wl],
// optionally the final 32->2 classifier.
template<int FSELF, bool PRE, bool FINAL>
__global__ __launch_bounds__(256, 4)
void k_sage(const unsigned* __restrict__ eb, const int* __restrict__ bbase,
            const float* __restrict__ src,   // [*,32] gather source
            const float* __restrict__ xd,    // [n,FSELF] self feats
            const float* __restrict__ wl,    // [32,32] (!PRE)
            const float* __restrict__ wr,    // [FSELF,32]
            const float* __restrict__ b,     // [32]
            float* __restrict__ y,           // [n,32] or [n,2] (FINAL)
            const float* __restrict__ wo,    // [32,2] (FINAL)
            const float* __restrict__ bo,    // [2]    (FINAL)
            int n) {
    __shared__ float acc[256 * PADROW];
    int t = threadIdx.x;
    int bkt = blockIdx.x;
    int e0 = bbase[bkt], e1 = bbase[bkt + 1];

    for (int i = t; i < 256 * PADROW; i += 256) acc[i] = 0.0f;
    __syncthreads();

    int sub  = t >> 3;   // edge slot 0..31
    int lane = t & 7;    // float4 index within row
    for (int ebase = e0; ebase < e1; ebase += 128) {
        unsigned p[4]; float4 v[4]; bool ok[4];
#pragma unroll
        for (int u = 0; u < 4; ++u) {
            int e = ebase + u * 32 + sub;
            ok[u] = e < e1;
            p[u] = eb[ok[u] ? e : e1 - 1];
        }
#pragma unroll
        for (int u = 0; u < 4; ++u) {
            int s = (int)(p[u] >> 8);
            v[u] = *(const float4*)(src + (size_t)s * HID + lane * 4);
        }
#pragma unroll
        for (int u = 0; u < 4; ++u) {
            if (ok[u]) {
                int dl = (int)(p[u] & 255);
                float* a = &acc[dl * PADROW + lane * 4];
                unsafeAtomicAdd(a + 0, v[u].x);
                unsafeAtomicAdd(a + 1, v[u].y);
                unsafeAtomicAdd(a + 2, v[u].z);
                unsafeAtomicAdd(a + 3, v[u].w);
                if (lane == 0) unsafeAtomicAdd(&acc[dl * PADROW + 32], 1.0f);
            }
        }
    }
    __syncthreads();

    int node = bkt * 256 + t;
    if (node >= n) return;

    float inv = 1.0f / fmaxf(acc[t * PADROW + 32], 1.0f);
    float am[HID];
#pragma unroll
    for (int j = 0; j < HID; ++j) am[j] = acc[t * PADROW + j] * inv;

    float s[HID];
#pragma unroll
    for (int j = 0; j < HID; ++j) s[j] = b[j];
    if (PRE) {
#pragma unroll
        for (int j = 0; j < HID; ++j) s[j] += am[j];
    } else {
#pragma unroll
        for (int k = 0; k < HID; ++k) {
            float a = am[k];
            const float* wrow = wl + k * HID;
#pragma unroll
            for (int j = 0; j < HID; ++j) s[j] = __builtin_fmaf(a, wrow[j], s[j]);
        }
    }

    const float4* xr = (const float4*)(xd + (size_t)node * FSELF);
#pragma unroll
    for (int k4 = 0; k4 < FSELF / 4; ++k4) {
        float4 xv = xr[k4];
        const float* wrow = wr + k4 * 4 * HID;
#pragma unroll
        for (int j = 0; j < HID; ++j) s[j] = __builtin_fmaf(xv.x, wrow[j], s[j]);
#pragma unroll
        for (int j = 0; j < HID; ++j) s[j] = __builtin_fmaf(xv.y, wrow[HID + j], s[j]);
#pragma unroll
        for (int j = 0; j < HID; ++j) s[j] = __builtin_fmaf(xv.z, wrow[2 * HID + j], s[j]);
#pragma unroll
        for (int j = 0; j < HID; ++j) s[j] = __builtin_fmaf(xv.w, wrow[3 * HID + j], s[j]);
    }
#pragma unroll
    for (int j = 0; j < HID; ++j) s[j] = fmaxf(s[j], 0.0f);

    if (!FINAL) {
        float4* yr = (float4*)(y + (size_t)node * HID);
#pragma unroll
        for (int j = 0; j < HID; j += 4)
            yr[j / 4] = make_float4(s[j], s[j + 1], s[j + 2], s[j + 3]);
    } else {
        float o0 = bo[0], o1 = bo[1];
#pragma unroll
        for (int j = 0; j < HID; ++j) {
            o0 = __builtin_fmaf(s[j], wo[j * 2 + 0], o0);
            o1 = __builtin_fmaf(s[j], wo[j * 2 + 1], o1);
        }
        y[(size_t)node * 2 + 0] = o0;
        y[(size_t)node * 2 + 1] = o1;
    }
}

// ============================================================================

extern "C" void kernel_launch(void* const* d_in, const int* in_sizes, int n_in,
                              void* d_out, int out_size, void* d_ws, size_t ws_size,
                              hipStream_t stream) {
    const float* x_addr  = (const float*)d_in[0];
    const float* x_tx    = (const float*)d_in[1];
    const int*   ei_at   = (const int*)d_in[2];
    const int*   ei_ta   = (const int*)d_in[3];
    const float* w1_tx_l = (const float*)d_in[4];  const float* b1_tx = (const float*)d_in[5];
    const float* w1_tx_r = (const float*)d_in[6];
    const float* w1_ad_l = (const float*)d_in[7];  const float* b1_ad = (const float*)d_in[8];
    const float* w1_ad_r = (const float*)d_in[9];
    const float* w2_tx_l = (const float*)d_in[10]; const float* b2_tx = (const float*)d_in[11];
    const float* w2_tx_r = (const float*)d_in[12];
    const float* w2_ad_l = (const float*)d_in[13]; const float* b2_ad = (const float*)d_in[14];
    const float* w2_ad_r = (const float*)d_in[15];
    // d_in[16..18] unused (w3_tx_*)
    const float* w3_ad_l = (const float*)d_in[19]; const float* b3_ad = (const float*)d_in[20];
    const float* w3_ad_r = (const float*)d_in[21];
    const float* w_out   = (const float*)d_in[22]; const float* b_out = (const float*)d_in[23];
    float* out = (float*)d_out;

    // ---- workspace carve ----
    char* base = (char*)d_ws;
    int* bcnt   = (int*)base;  base += (size_t)(2 * NB) * 4;
    int* bbase  = (int*)base;  base += (size_t)(2 * (NB + 1)) * 4;
    int* gcur   = (int*)base;  base += (size_t)(2 * NB) * 4;
    unsigned* eb_at = (unsigned*)base;  base += (size_t)NEDGE * 4;
    unsigned* eb_ta = (unsigned*)base;  base += (size_t)NEDGE * 4;
    base = (char*)(((size_t)base + 255) & ~(size_t)255);
    const size_t SLOT = (size_t)400000 * HID;
    float* S0 = (float*)base;   // pre scratch (layer 1)
    float* S1 = S0 + SLOT;      // tx
    float* S2 = S1 + SLOT;      // ad -> ad2 (in place)
    float* S3 = S2 + SLOT;      // tx2

    dim3 blk(256);
    int gN = cdiv_host(400000, 256);              // 1563
    const int GH = 96, GD = 192;
    const int* bb_tx = bbase;                     // bbase for dst=tx
    const int* bb_ad = bbase + (NB + 1);          // bbase for dst=ad

    // ---- bucketed edge build (both edge types) ----
    hipMemsetAsync(bcnt, 0, (size_t)(2 * NB) * 4, stream);
    k_hist<<<2 * GH, blk, 0, stream>>>(ei_at + NEDGE, ei_ta + NEDGE, bcnt, GH);
    k_scan_nb<<<2, blk, 0, stream>>>(bcnt, bbase, gcur);
    k_dist<<<2 * GD, blk, 0, stream>>>(ei_at, ei_ta, gcur, eb_at, eb_ta, GD);

    // ---- layer 1: tx = relu(mean_at(x_addr@w1_tx_l) + x_tx@w1_tx_r + b1_tx) ----
    k_linear<FIN><<<gN, blk, 0, stream>>>(x_addr, w1_tx_l, S0, NADDR);
    k_sage<FIN, true, false><<<NB, blk, 0, stream>>>(eb_at, bb_tx, S0, x_tx, nullptr,
                                                     w1_tx_r, b1_tx, S1, nullptr, nullptr, NTX);
    // ---- layer 1: ad ----
    k_linear<FIN><<<gN, blk, 0, stream>>>(x_tx, w1_ad_l, S0, NTX);
    k_sage<FIN, true, false><<<NB, blk, 0, stream>>>(eb_ta, bb_ad, S0, x_addr, nullptr,
                                                     w1_ad_r, b1_ad, S2, nullptr, nullptr, NADDR);
    // ---- layer 2: tx2 = relu(mean_at(ad)@w2_tx_l + tx@w2_tx_r + b2_tx) -> S3 ----
    k_sage<HID, false, false><<<NB, blk, 0, stream>>>(eb_at, bb_tx, S2, S1, w2_tx_l,
                                                      w2_tx_r, b2_tx, S3, nullptr, nullptr, NTX);
    // ---- layer 2: ad2 = relu(mean_ta(tx)@w2_ad_l + ad@w2_ad_r + b2_ad) -> S2 in place ----
    k_sage<HID, false, false><<<NB, blk, 0, stream>>>(eb_ta, bb_ad, S1, S2, w2_ad_l,
                                                      w2_ad_r, b2_ad, S2, nullptr, nullptr, NADDR);
    // ---- layer 3 + classifier: ad3 -> out ----
    k_sage<HID, false, true><<<NB, blk, 0, stream>>>(eb_ta, bb_ad, S3, S2, w3_ad_l,
                                                     w3_ad_r, b3_ad, out, w_out, b_out, NADDR);
}

// Round 6
// 923.012 us; speedup vs baseline: 1.8546x; 1.8546x over previous
//
#include <hip/hip_runtime.h>

#define NADDR 400000
#define NTX   400000
#define NEDGE 1500000
#define FIN   64
#define HID   32
#define NB    1563        // buckets per node type; 256 nodes per bucket

static inline int cdiv_host(long a, int b) { return (int)((a + b - 1) / b); }

// ================= bucketed CSR build (verified round-4 chain) ==============

__global__ void k_hist(const int* __restrict__ at_dst, const int* __restrict__ ta_dst,
                       int* __restrict__ bcnt /*[2*NB]*/, int GH) {
    __shared__ int h[NB];
    bool wh = blockIdx.x >= GH;
    int blk = blockIdx.x - (wh ? GH : 0);
    const int* dst = wh ? ta_dst : at_dst;
    for (int i = threadIdx.x; i < NB; i += 256) h[i] = 0;
    __syncthreads();
    for (long e = (long)blk * 256 + threadIdx.x; e < NEDGE; e += (long)GH * 256)
        atomicAdd(&h[dst[e] >> 8], 1);
    __syncthreads();
    int* g = bcnt + (wh ? NB : 0);
    for (int i = threadIdx.x; i < NB; i += 256) {
        int v = h[i];
        if (v) atomicAdd(&g[i], v);
    }
}

__global__ void k_scan_nb(const int* __restrict__ bcnt, int* __restrict__ bbase,
                          int* __restrict__ gcur) {
    __shared__ int sm[256];
    __shared__ int carry;
    int w = blockIdx.x;
    int t = threadIdx.x;
    if (t == 0) carry = 0;
    __syncthreads();
    for (int base = 0; base < NB; base += 256) {
        int i = base + t;
        int v = (i < NB) ? bcnt[w * NB + i] : 0;
        sm[t] = v;
        __syncthreads();
        for (int off = 1; off < 256; off <<= 1) {
            int x = (t >= off) ? sm[t - off] : 0;
            __syncthreads();
            sm[t] += x;
            __syncthreads();
        }
        int excl = sm[t] - v + carry;
        if (i < NB) { bbase[w * (NB + 1) + i] = excl; gcur[w * NB + i] = excl; }
        int tot = sm[255];
        __syncthreads();
        if (t == 0) carry += tot;
        __syncthreads();
    }
    if (t == 0) bbase[w * (NB + 1) + NB] = NEDGE;
}

__global__ void k_dist(const int* __restrict__ ei_at, const int* __restrict__ ei_ta,
                       int* __restrict__ gcur, unsigned* __restrict__ eb_at,
                       unsigned* __restrict__ eb_ta, int GD) {
    __shared__ int h[NB];
    __shared__ int bs[NB];
    bool wh = blockIdx.x >= GD;
    int blk = blockIdx.x - (wh ? GD : 0);
    const int* ei = wh ? ei_ta : ei_at;
    unsigned* eb = wh ? eb_ta : eb_at;
    for (int i = threadIdx.x; i < NB; i += 256) h[i] = 0;
    __syncthreads();
    long e0 = (long)blk * 256 + threadIdx.x;
    long stride = (long)GD * 256;
    for (long e = e0; e < NEDGE; e += stride)
        atomicAdd(&h[ei[NEDGE + e] >> 8], 1);
    __syncthreads();
    int* gc = gcur + (wh ? NB : 0);
    for (int i = threadIdx.x; i < NB; i += 256) {
        int c = h[i];
        bs[i] = c ? atomicAdd(&gc[i], c) : 0;
        h[i] = 0;
    }
    __syncthreads();
    for (long e = e0; e < NEDGE; e += stride) {
        int d = ei[NEDGE + e];
        int s = ei[e];
        int b = d >> 8;
        int r = atomicAdd(&h[b], 1);
        eb[bs[b] + r] = ((unsigned)s << 8) | (unsigned)(d & 255);
    }
}

__global__ void k_csrb(const unsigned* __restrict__ eb_at, const unsigned* __restrict__ eb_ta,
                       const int* __restrict__ bbase,
                       int* __restrict__ rp_tx, int* __restrict__ rp_ad,
                       int* __restrict__ col_at, int* __restrict__ col_ta) {
    __shared__ int deg[256];
    __shared__ int cur[256];
    __shared__ int sm[256];
    bool wh = blockIdx.x >= NB;
    int b = blockIdx.x - (wh ? NB : 0);
    const unsigned* eb = wh ? eb_ta : eb_at;
    int* rp  = wh ? rp_ad  : rp_tx;
    int* col = wh ? col_ta : col_at;
    const int* bb = bbase + (wh ? (NB + 1) : 0);
    int e0 = bb[b], e1 = bb[b + 1];
    int t = threadIdx.x;
    deg[t] = 0;
    __syncthreads();
    for (int e = e0 + t; e < e1; e += 256)
        atomicAdd(&deg[eb[e] & 255], 1);
    __syncthreads();
    int v = deg[t];
    sm[t] = v;
    __syncthreads();
    for (int off = 1; off < 256; off <<= 1) {
        int x = (t >= off) ? sm[t - off] : 0;
        __syncthreads();
        sm[t] += x;
        __syncthreads();
    }
    int excl = sm[t] - v;
    int node = b * 256 + t;
    if (node < 400000) rp[node] = e0 + excl;
    cur[t] = e0 + excl;
    __syncthreads();
    for (int e = e0 + t; e < e1; e += 256) {
        unsigned p = eb[e];
        int idx = atomicAdd(&cur[p & 255], 1);
        col[idx] = (int)(p >> 8);
    }
    if (t == 0 && b == 0) rp[400000] = NEDGE;
}

// ================= dense pre-transforms (thread-per-node, no shuffles) ======
// outa = x@wa (+ba); if DUAL also outb = x@wb + bb. outa may alias x (row is
// fully read into registers before the row write).
template<int F, bool DUAL>
__global__ void k_pre(const float* __restrict__ x,
                      const float* __restrict__ wa, const float* __restrict__ ba,
                      float* __restrict__ outa,
                      const float* __restrict__ wb, const float* __restrict__ bb,
                      float* __restrict__ outb, int n) {
    int i = blockIdx.x * 256 + threadIdx.x;
    if (i >= n) return;
    const float4* xr = (const float4*)(x + (size_t)i * F);
    float aa[HID], ab[DUAL ? HID : 1];
#pragma unroll
    for (int j = 0; j < HID; ++j) aa[j] = ba ? ba[j] : 0.0f;
    if (DUAL) {
#pragma unroll
        for (int j = 0; j < HID; ++j) ab[j] = bb[j];
    }
    for (int k4 = 0; k4 < F / 4; ++k4) {
        float4 xv = xr[k4];
        const float* wra = wa + k4 * 4 * HID;
#pragma unroll
        for (int j = 0; j < HID; ++j) aa[j] = __builtin_fmaf(xv.x, wra[j], aa[j]);
#pragma unroll
        for (int j = 0; j < HID; ++j) aa[j] = __builtin_fmaf(xv.y, wra[HID + j], aa[j]);
#pragma unroll
        for (int j = 0; j < HID; ++j) aa[j] = __builtin_fmaf(xv.z, wra[2 * HID + j], aa[j]);
#pragma unroll
        for (int j = 0; j < HID; ++j) aa[j] = __builtin_fmaf(xv.w, wra[3 * HID + j], aa[j]);
        if (DUAL) {
            const float* wrb = wb + k4 * 4 * HID;
#pragma unroll
            for (int j = 0; j < HID; ++j) ab[j] = __builtin_fmaf(xv.x, wrb[j], ab[j]);
#pragma unroll
            for (int j = 0; j < HID; ++j) ab[j] = __builtin_fmaf(xv.y, wrb[HID + j], ab[j]);
#pragma unroll
            for (int j = 0; j < HID; ++j) ab[j] = __builtin_fmaf(xv.z, wrb[2 * HID + j], ab[j]);
#pragma unroll
            for (int j = 0; j < HID; ++j) ab[j] = __builtin_fmaf(xv.w, wrb[3 * HID + j], ab[j]);
        }
    }
    float4* ya = (float4*)(outa + (size_t)i * HID);
#pragma unroll
    for (int j = 0; j < HID; j += 4)
        ya[j / 4] = make_float4(aa[j], aa[j + 1], aa[j + 2], aa[j + 3]);
    if (DUAL) {
        float4* yb = (float4*)(outb + (size_t)i * HID);
#pragma unroll
        for (int j = 0; j < HID; j += 4)
            yb[j / 4] = make_float4(ab[j], ab[j + 1], ab[j + 2], ab[j + 3]);
    }
}

// ================= shuffle-free SAGE aggregation ============================
// 8 lanes per dst node, float4 row slices. 8-deep clamped edge unroll ->
// up to 64 cache lines in flight per wave. y = relu(mean(gather preL) + preR).
// y may alias preR (same-row in-place). FINAL applies the 32->2 classifier.
template<bool FINAL>
__global__ __launch_bounds__(256)
void k_agg(const int* __restrict__ rp, const int* __restrict__ col,
           const float* __restrict__ preL, const float* __restrict__ preR,
           float* __restrict__ y,
           const float* __restrict__ wo, const float* __restrict__ bo, int n) {
    int t = blockIdx.x * 256 + threadIdx.x;
    int g = t >> 3;     // node
    int u = t & 7;      // float4 slot within row
    if (g >= n) return;
    int p0 = rp[g], p1 = rp[g + 1];

    float ax = 0.0f, ay = 0.0f, az = 0.0f, aw = 0.0f;
    for (int k = p0; k < p1; k += 8) {
        int last = p1 - 1;
        int idx[8];
#pragma unroll
        for (int q = 0; q < 8; ++q) {
            int e = k + q;
            idx[q] = col[e < p1 ? e : last];   // broadcast within 8-lane group
        }
        float4 v[8];
#pragma unroll
        for (int q = 0; q < 8; ++q)
            v[q] = *(const float4*)(preL + (size_t)idx[q] * HID + u * 4);
#pragma unroll
        for (int q = 0; q < 8; ++q) {
            if (k + q < p1) {
                ax += v[q].x; ay += v[q].y; az += v[q].z; aw += v[q].w;
            }
        }
    }
    float inv = 1.0f / fmaxf((float)(p1 - p0), 1.0f);
    float4 r = *(const float4*)(preR + (size_t)g * HID + u * 4);
    float4 h;
    h.x = fmaxf(__builtin_fmaf(ax, inv, r.x), 0.0f);
    h.y = fmaxf(__builtin_fmaf(ay, inv, r.y), 0.0f);
    h.z = fmaxf(__builtin_fmaf(az, inv, r.z), 0.0f);
    h.w = fmaxf(__builtin_fmaf(aw, inv, r.w), 0.0f);

    if (!FINAL) {
        *(float4*)(y + (size_t)g * HID + u * 4) = h;
    } else {
        int j = u * 4;
        float o0 = h.x * wo[(j + 0) * 2 + 0] + h.y * wo[(j + 1) * 2 + 0]
                 + h.z * wo[(j + 2) * 2 + 0] + h.w * wo[(j + 3) * 2 + 0];
        float o1 = h.x * wo[(j + 0) * 2 + 1] + h.y * wo[(j + 1) * 2 + 1]
                 + h.z * wo[(j + 2) * 2 + 1] + h.w * wo[(j + 3) * 2 + 1];
#pragma unroll
        for (int m = 4; m >= 1; m >>= 1) {
            o0 += __shfl_xor(o0, m, 8);
            o1 += __shfl_xor(o1, m, 8);
        }
        if (u == 0) {
            y[(size_t)g * 2 + 0] = o0 + bo[0];
            y[(size_t)g * 2 + 1] = o1 + bo[1];
        }
    }
}

// ============================================================================

extern "C" void kernel_launch(void* const* d_in, const int* in_sizes, int n_in,
                              void* d_out, int out_size, void* d_ws, size_t ws_size,
                              hipStream_t stream) {
    const float* x_addr  = (const float*)d_in[0];
    const float* x_tx    = (const float*)d_in[1];
    const int*   ei_at   = (const int*)d_in[2];
    const int*   ei_ta   = (const int*)d_in[3];
    const float* w1_tx_l = (const float*)d_in[4];  const float* b1_tx = (const float*)d_in[5];
    const float* w1_tx_r = (const float*)d_in[6];
    const float* w1_ad_l = (const float*)d_in[7];  const float* b1_ad = (const float*)d_in[8];
    const float* w1_ad_r = (const float*)d_in[9];
    const float* w2_tx_l = (const float*)d_in[10]; const float* b2_tx = (const float*)d_in[11];
    const float* w2_tx_r = (const float*)d_in[12];
    const float* w2_ad_l = (const float*)d_in[13]; const float* b2_ad = (const float*)d_in[14];
    const float* w2_ad_r = (const float*)d_in[15];
    // d_in[16..18] unused (w3_tx_*)
    const float* w3_ad_l = (const float*)d_in[19]; const float* b3_ad = (const float*)d_in[20];
    const float* w3_ad_r = (const float*)d_in[21];
    const float* w_out   = (const float*)d_in[22]; const float* b_out = (const float*)d_in[23];
    float* out = (float*)d_out;

    // ---- workspace carve (~233 MB, same scale as round-4's verified layout) ----
    char* base = (char*)d_ws;
    int* bcnt   = (int*)base;  base += (size_t)(2 * NB) * 4;
    int* bbase  = (int*)base;  base += (size_t)(2 * (NB + 1)) * 4;
    int* gcur   = (int*)base;  base += (size_t)(2 * NB) * 4;
    int* rp_tx  = (int*)base;  base += (size_t)(NTX + 1) * 4;
    int* rp_ad  = (int*)base;  base += (size_t)(NADDR + 1) * 4;
    int* col_at = (int*)base;  base += (size_t)NEDGE * 4;
    int* col_ta = (int*)base;  base += (size_t)NEDGE * 4;
    unsigned* eb_at = (unsigned*)base;  base += (size_t)NEDGE * 4;
    unsigned* eb_ta = (unsigned*)base;  base += (size_t)NEDGE * 4;
    base = (char*)(((size_t)base + 255) & ~(size_t)255);
    const size_t SLOT = (size_t)400000 * HID;
    float* A = (float*)base;
    float* B = A + SLOT;
    float* C = B + SLOT;
    float* D = C + SLOT;

    dim3 blk(256);
    int gN = cdiv_host(400000, 256);              // 1563
    int gG = cdiv_host((long)400000 * 8, 256);    // 12500
    const int GH = 96, GD = 192;
    const int* bb_tx = bbase;
    const int* bb_ad = bbase + (NB + 1);
    (void)bb_tx; (void)bb_ad;

    // ---- bucketed CSR build ----
    hipMemsetAsync(bcnt, 0, (size_t)(2 * NB) * 4, stream);
    k_hist<<<2 * GH, blk, 0, stream>>>(ei_at + NEDGE, ei_ta + NEDGE, bcnt, GH);
    k_scan_nb<<<2, blk, 0, stream>>>(bcnt, bbase, gcur);
    k_dist<<<2 * GD, blk, 0, stream>>>(ei_at, ei_ta, gcur, eb_at, eb_ta, GD);
    k_csrb<<<2 * NB, blk, 0, stream>>>(eb_at, eb_ta, bbase, rp_tx, rp_ad, col_at, col_ta);

    // ---- layer 1 pre-transforms ----
    // A = x_addr@w1_tx_l (preL for tx)       B = x_addr@w1_ad_r + b1_ad (preR for ad)
    k_pre<FIN, true><<<gN, blk, 0, stream>>>(x_addr, w1_tx_l, nullptr, A,
                                             w1_ad_r, b1_ad, B, NADDR);
    // C = x_tx@w1_ad_l (preL for ad)         D = x_tx@w1_tx_r + b1_tx (preR for tx)
    k_pre<FIN, true><<<gN, blk, 0, stream>>>(x_tx, w1_ad_l, nullptr, C,
                                             w1_tx_r, b1_tx, D, NTX);
    // ---- layer 1 aggregations ----
    k_agg<false><<<gG, blk, 0, stream>>>(rp_tx, col_at, A, D, D, nullptr, nullptr, NTX);   // D = tx
    k_agg<false><<<gG, blk, 0, stream>>>(rp_ad, col_ta, C, B, B, nullptr, nullptr, NADDR); // B = ad

    // ---- layer 2 pre-transforms ----
    // A = tx@w2_ad_l (preL for ad2)          C = tx@w2_tx_r + b2_tx (preR for tx2)
    k_pre<HID, true><<<gN, blk, 0, stream>>>(D, w2_ad_l, nullptr, A,
                                             w2_tx_r, b2_tx, C, NTX);
    // B = ad@w2_tx_l in-place (preL for tx2) D = ad@w2_ad_r + b2_ad (preR for ad2)
    k_pre<HID, true><<<gN, blk, 0, stream>>>(B, w2_tx_l, nullptr, B,
                                             w2_ad_r, b2_ad, D, NADDR);
    // ---- layer 2 aggregations ----
    k_agg<false><<<gG, blk, 0, stream>>>(rp_tx, col_at, B, C, C, nullptr, nullptr, NTX);   // C = tx2
    k_agg<false><<<gG, blk, 0, stream>>>(rp_ad, col_ta, A, D, D, nullptr, nullptr, NADDR); // D = ad2

    // ---- layer 3 pre-transforms ----
    k_pre<HID, false><<<gN, blk, 0, stream>>>(C, w3_ad_l, nullptr, A,
                                              nullptr, nullptr, nullptr, NTX);   // A = preL
    k_pre<HID, false><<<gN, blk, 0, stream>>>(D, w3_ad_r, b3_ad, B,
                                              nullptr, nullptr, nullptr, NADDR); // B = preR
    // ---- layer 3 aggregation + classifier ----
    k_agg<true><<<gG, blk, 0, stream>>>(rp_ad, col_ta, A, B, out, w_out, b_out, NADDR);
}

// Round 7
// 765.707 us; speedup vs baseline: 2.2356x; 1.2054x over previous
//
#include <hip/hip_runtime.h>

#define NADDR 400000
#define NTX   400000
#define NEDGE 1500000
#define FIN   64
#define HID   32
#define NB    1563        // buckets per node type; 256 nodes per bucket
#define LSTR  35          // LDS row stride (floats): (3t+k)%32 -> 2-way, free

static inline int cdiv_host(long a, int b) { return (int)((a + b - 1) / b); }

// ================= bucketed CSR build (verified round-4 chain) ==============

__global__ void k_hist(const int* __restrict__ at_dst, const int* __restrict__ ta_dst,
                       int* __restrict__ bcnt /*[2*NB]*/, int GH) {
    __shared__ int h[NB];
    bool wh = blockIdx.x >= GH;
    int blk = blockIdx.x - (wh ? GH : 0);
    const int* dst = wh ? ta_dst : at_dst;
    for (int i = threadIdx.x; i < NB; i += 256) h[i] = 0;
    __syncthreads();
    for (long e = (long)blk * 256 + threadIdx.x; e < NEDGE; e += (long)GH * 256)
        atomicAdd(&h[dst[e] >> 8], 1);
    __syncthreads();
    int* g = bcnt + (wh ? NB : 0);
    for (int i = threadIdx.x; i < NB; i += 256) {
        int v = h[i];
        if (v) atomicAdd(&g[i], v);
    }
}

__global__ void k_scan_nb(const int* __restrict__ bcnt, int* __restrict__ bbase,
                          int* __restrict__ gcur) {
    __shared__ int sm[256];
    __shared__ int carry;
    int w = blockIdx.x;
    int t = threadIdx.x;
    if (t == 0) carry = 0;
    __syncthreads();
    for (int base = 0; base < NB; base += 256) {
        int i = base + t;
        int v = (i < NB) ? bcnt[w * NB + i] : 0;
        sm[t] = v;
        __syncthreads();
        for (int off = 1; off < 256; off <<= 1) {
            int x = (t >= off) ? sm[t - off] : 0;
            __syncthreads();
            sm[t] += x;
            __syncthreads();
        }
        int excl = sm[t] - v + carry;
        if (i < NB) { bbase[w * (NB + 1) + i] = excl; gcur[w * NB + i] = excl; }
        int tot = sm[255];
        __syncthreads();
        if (t == 0) carry += tot;
        __syncthreads();
    }
    if (t == 0) bbase[w * (NB + 1) + NB] = NEDGE;
}

__global__ void k_dist(const int* __restrict__ ei_at, const int* __restrict__ ei_ta,
                       int* __restrict__ gcur, unsigned* __restrict__ eb_at,
                       unsigned* __restrict__ eb_ta, int GD) {
    __shared__ int h[NB];
    __shared__ int bs[NB];
    bool wh = blockIdx.x >= GD;
    int blk = blockIdx.x - (wh ? GD : 0);
    const int* ei = wh ? ei_ta : ei_at;
    unsigned* eb = wh ? eb_ta : eb_at;
    for (int i = threadIdx.x; i < NB; i += 256) h[i] = 0;
    __syncthreads();
    long e0 = (long)blk * 256 + threadIdx.x;
    long stride = (long)GD * 256;
    for (long e = e0; e < NEDGE; e += stride)
        atomicAdd(&h[ei[NEDGE + e] >> 8], 1);
    __syncthreads();
    int* gc = gcur + (wh ? NB : 0);
    for (int i = threadIdx.x; i < NB; i += 256) {
        int c = h[i];
        bs[i] = c ? atomicAdd(&gc[i], c) : 0;
        h[i] = 0;
    }
    __syncthreads();
    for (long e = e0; e < NEDGE; e += stride) {
        int d = ei[NEDGE + e];
        int s = ei[e];
        int b = d >> 8;
        int r = atomicAdd(&h[b], 1);
        eb[bs[b] + r] = ((unsigned)s << 8) | (unsigned)(d & 255);
    }
}

__global__ void k_csrb(const unsigned* __restrict__ eb_at, const unsigned* __restrict__ eb_ta,
                       const int* __restrict__ bbase,
                       int* __restrict__ rp_tx, int* __restrict__ rp_ad,
                       int* __restrict__ col_at, int* __restrict__ col_ta) {
    __shared__ int deg[256];
    __shared__ int cur[256];
    __shared__ int sm[256];
    bool wh = blockIdx.x >= NB;
    int b = blockIdx.x - (wh ? NB : 0);
    const unsigned* eb = wh ? eb_ta : eb_at;
    int* rp  = wh ? rp_ad  : rp_tx;
    int* col = wh ? col_ta : col_at;
    const int* bb = bbase + (wh ? (NB + 1) : 0);
    int e0 = bb[b], e1 = bb[b + 1];
    int t = threadIdx.x;
    deg[t] = 0;
    __syncthreads();
    for (int e = e0 + t; e < e1; e += 256)
        atomicAdd(&deg[eb[e] & 255], 1);
    __syncthreads();
    int v = deg[t];
    sm[t] = v;
    __syncthreads();
    for (int off = 1; off < 256; off <<= 1) {
        int x = (t >= off) ? sm[t - off] : 0;
        __syncthreads();
        sm[t] += x;
        __syncthreads();
    }
    int excl = sm[t] - v;
    int node = b * 256 + t;
    if (node < 400000) rp[node] = e0 + excl;
    cur[t] = e0 + excl;
    __syncthreads();
    for (int e = e0 + t; e < e1; e += 256) {
        unsigned p = eb[e];
        int idx = atomicAdd(&cur[p & 255], 1);
        col[idx] = (int)(p >> 8);
    }
    if (t == 0 && b == 0) rp[400000] = NEDGE;
}

// ================= LDS-tiled dense pre-transforms ===========================
// Block = 256 threads = 256 rows. K-tiles of 32 feats staged in LDS with
// fully coalesced global loads; outputs staged back through LDS for full-line
// coalesced stores (no RFO). outa may alias x: block reads only its own rows,
// all reads complete (barrier) before any store.
template<int F, bool DUAL>
__global__ __launch_bounds__(256)
void k_pre(const float* __restrict__ x,
           const float* __restrict__ wa, const float* __restrict__ ba,
           float* __restrict__ outa,
           const float* __restrict__ wb, const float* __restrict__ bb,
           float* __restrict__ outb, int n) {
    __shared__ float xs[256 * LSTR];
    int t = threadIdx.x;
    long row0 = (long)blockIdx.x * 256;

    float aa[HID], ab[DUAL ? HID : 1];
#pragma unroll
    for (int j = 0; j < HID; ++j) aa[j] = ba ? ba[j] : 0.0f;
    if (DUAL) {
#pragma unroll
        for (int j = 0; j < HID; ++j) ab[j] = bb[j];
    }

    for (int kt = 0; kt < F / 32; ++kt) {
        // ---- stage K-tile [256 rows x 32 feats], coalesced ----
#pragma unroll
        for (int sub = 0; sub < 8; ++sub) {
            int f = sub * 256 + t;          // float4 slot in tile
            int r = f >> 3, k4 = f & 7;
            long gr = row0 + r;
            if (gr >= n) gr = n - 1;
            float4 v = *(const float4*)(x + gr * F + kt * 32 + k4 * 4);
            float* d = &xs[r * LSTR + k4 * 4];
            d[0] = v.x; d[1] = v.y; d[2] = v.z; d[3] = v.w;
        }
        __syncthreads();
        // ---- compute: this thread's row from LDS ----
        const float* xr = &xs[t * LSTR];
        const float* wka = wa + kt * 32 * HID;
        const float* wkb = DUAL ? (wb + kt * 32 * HID) : nullptr;
#pragma unroll
        for (int k = 0; k < 32; ++k) {
            float xk = xr[k];
            const float* wra = wka + k * HID;
#pragma unroll
            for (int j = 0; j < HID; ++j) aa[j] = __builtin_fmaf(xk, wra[j], aa[j]);
            if (DUAL) {
                const float* wrb = wkb + k * HID;
#pragma unroll
                for (int j = 0; j < HID; ++j) ab[j] = __builtin_fmaf(xk, wrb[j], ab[j]);
            }
        }
        __syncthreads();
    }

    // ---- store outa via LDS, full-line coalesced ----
#pragma unroll
    for (int j = 0; j < HID; ++j) xs[t * LSTR + j] = aa[j];
    __syncthreads();
#pragma unroll
    for (int sub = 0; sub < 8; ++sub) {
        int f = sub * 256 + t;
        int r = f >> 3, k4 = f & 7;
        long gr = row0 + r;
        if (gr < n) {
            const float* s = &xs[r * LSTR + k4 * 4];
            *(float4*)(outa + gr * HID + k4 * 4) = make_float4(s[0], s[1], s[2], s[3]);
        }
    }
    if (DUAL) {
        __syncthreads();
#pragma unroll
        for (int j = 0; j < HID; ++j) xs[t * LSTR + j] = ab[j];
        __syncthreads();
#pragma unroll
        for (int sub = 0; sub < 8; ++sub) {
            int f = sub * 256 + t;
            int r = f >> 3, k4 = f & 7;
            long gr = row0 + r;
            if (gr < n) {
                const float* s = &xs[r * LSTR + k4 * 4];
                *(float4*)(outb + gr * HID + k4 * 4) = make_float4(s[0], s[1], s[2], s[3]);
            }
        }
    }
}

// ================= shuffle-free SAGE aggregation ============================
template<bool FINAL>
__global__ __launch_bounds__(256)
void k_agg(const int* __restrict__ rp, const int* __restrict__ col,
           const float* __restrict__ preL, const float* __restrict__ preR,
           float* __restrict__ y,
           const float* __restrict__ wo, const float* __restrict__ bo, int n) {
    int t = blockIdx.x * 256 + threadIdx.x;
    int g = t >> 3;     // node
    int u = t & 7;      // float4 slot within row
    if (g >= n) return;
    int p0 = rp[g], p1 = rp[g + 1];

    float ax = 0.0f, ay = 0.0f, az = 0.0f, aw = 0.0f;
    for (int k = p0; k < p1; k += 8) {
        int last = p1 - 1;
        int idx[8];
#pragma unroll
        for (int q = 0; q < 8; ++q) {
            int e = k + q;
            idx[q] = col[e < p1 ? e : last];
        }
        float4 v[8];
#pragma unroll
        for (int q = 0; q < 8; ++q)
            v[q] = *(const float4*)(preL + (size_t)idx[q] * HID + u * 4);
#pragma unroll
        for (int q = 0; q < 8; ++q) {
            if (k + q < p1) {
                ax += v[q].x; ay += v[q].y; az += v[q].z; aw += v[q].w;
            }
        }
    }
    float inv = 1.0f / fmaxf((float)(p1 - p0), 1.0f);
    float4 r = *(const float4*)(preR + (size_t)g * HID + u * 4);
    float4 h;
    h.x = fmaxf(__builtin_fmaf(ax, inv, r.x), 0.0f);
    h.y = fmaxf(__builtin_fmaf(ay, inv, r.y), 0.0f);
    h.z = fmaxf(__builtin_fmaf(az, inv, r.z), 0.0f);
    h.w = fmaxf(__builtin_fmaf(aw, inv, r.w), 0.0f);

    if (!FINAL) {
        *(float4*)(y + (size_t)g * HID + u * 4) = h;
    } else {
        int j = u * 4;
        float o0 = h.x * wo[(j + 0) * 2 + 0] + h.y * wo[(j + 1) * 2 + 0]
                 + h.z * wo[(j + 2) * 2 + 0] + h.w * wo[(j + 3) * 2 + 0];
        float o1 = h.x * wo[(j + 0) * 2 + 1] + h.y * wo[(j + 1) * 2 + 1]
                 + h.z * wo[(j + 2) * 2 + 1] + h.w * wo[(j + 3) * 2 + 1];
#pragma unroll
        for (int m = 4; m >= 1; m >>= 1) {
            o0 += __shfl_xor(o0, m, 8);
            o1 += __shfl_xor(o1, m, 8);
        }
        if (u == 0) {
            y[(size_t)g * 2 + 0] = o0 + bo[0];
            y[(size_t)g * 2 + 1] = o1 + bo[1];
        }
    }
}

// ============================================================================

extern "C" void kernel_launch(void* const* d_in, const int* in_sizes, int n_in,
                              void* d_out, int out_size, void* d_ws, size_t ws_size,
                              hipStream_t stream) {
    const float* x_addr  = (const float*)d_in[0];
    const float* x_tx    = (const float*)d_in[1];
    const int*   ei_at   = (const int*)d_in[2];
    const int*   ei_ta   = (const int*)d_in[3];
    const float* w1_tx_l = (const float*)d_in[4];  const float* b1_tx = (const float*)d_in[5];
    const float* w1_tx_r = (const float*)d_in[6];
    const float* w1_ad_l = (const float*)d_in[7];  const float* b1_ad = (const float*)d_in[8];
    const float* w1_ad_r = (const float*)d_in[9];
    const float* w2_tx_l = (const float*)d_in[10]; const float* b2_tx = (const float*)d_in[11];
    const float* w2_tx_r = (const float*)d_in[12];
    const float* w2_ad_l = (const float*)d_in[13]; const float* b2_ad = (const float*)d_in[14];
    const float* w2_ad_r = (const float*)d_in[15];
    // d_in[16..18] unused (w3_tx_*)
    const float* w3_ad_l = (const float*)d_in[19]; const float* b3_ad = (const float*)d_in[20];
    const float* w3_ad_r = (const float*)d_in[21];
    const float* w_out   = (const float*)d_in[22]; const float* b_out = (const float*)d_in[23];
    float* out = (float*)d_out;

    // ---- workspace carve ----
    char* base = (char*)d_ws;
    int* bcnt   = (int*)base;  base += (size_t)(2 * NB) * 4;
    int* bbase  = (int*)base;  base += (size_t)(2 * (NB + 1)) * 4;
    int* gcur   = (int*)base;  base += (size_t)(2 * NB) * 4;
    int* rp_tx  = (int*)base;  base += (size_t)(NTX + 1) * 4;
    int* rp_ad  = (int*)base;  base += (size_t)(NADDR + 1) * 4;
    int* col_at = (int*)base;  base += (size_t)NEDGE * 4;
    int* col_ta = (int*)base;  base += (size_t)NEDGE * 4;
    unsigned* eb_at = (unsigned*)base;  base += (size_t)NEDGE * 4;
    unsigned* eb_ta = (unsigned*)base;  base += (size_t)NEDGE * 4;
    base = (char*)(((size_t)base + 255) & ~(size_t)255);
    const size_t SLOT = (size_t)400000 * HID;
    float* A = (float*)base;
    float* B = A + SLOT;
    float* C = B + SLOT;
    float* D = C + SLOT;

    dim3 blk(256);
    int gN = cdiv_host(400000, 256);              // 1563
    int gG = cdiv_host((long)400000 * 8, 256);    // 12500
    const int GH = 96, GD = 192;

    // ---- bucketed CSR build ----
    hipMemsetAsync(bcnt, 0, (size_t)(2 * NB) * 4, stream);
    k_hist<<<2 * GH, blk, 0, stream>>>(ei_at + NEDGE, ei_ta + NEDGE, bcnt, GH);
    k_scan_nb<<<2, blk, 0, stream>>>(bcnt, bbase, gcur);
    k_dist<<<2 * GD, blk, 0, stream>>>(ei_at, ei_ta, gcur, eb_at, eb_ta, GD);
    k_csrb<<<2 * NB, blk, 0, stream>>>(eb_at, eb_ta, bbase, rp_tx, rp_ad, col_at, col_ta);

    // ---- layer 1 pre-transforms ----
    // A = x_addr@w1_tx_l (preL for tx)       B = x_addr@w1_ad_r + b1_ad (preR for ad)
    k_pre<FIN, true><<<gN, blk, 0, stream>>>(x_addr, w1_tx_l, nullptr, A,
                                             w1_ad_r, b1_ad, B, NADDR);
    // C = x_tx@w1_ad_l (preL for ad)         D = x_tx@w1_tx_r + b1_tx (preR for tx)
    k_pre<FIN, true><<<gN, blk, 0, stream>>>(x_tx, w1_ad_l, nullptr, C,
                                             w1_tx_r, b1_tx, D, NTX);
    // ---- layer 1 aggregations ----
    k_agg<false><<<gG, blk, 0, stream>>>(rp_tx, col_at, A, D, D, nullptr, nullptr, NTX);   // D = tx
    k_agg<false><<<gG, blk, 0, stream>>>(rp_ad, col_ta, C, B, B, nullptr, nullptr, NADDR); // B = ad

    // ---- layer 2 pre-transforms ----
    // A = tx@w2_ad_l (preL for ad2)          C = tx@w2_tx_r + b2_tx (preR for tx2)
    k_pre<HID, true><<<gN, blk, 0, stream>>>(D, w2_ad_l, nullptr, A,
                                             w2_tx_r, b2_tx, C, NTX);
    // B = ad@w2_tx_l in-place (preL for tx2) D = ad@w2_ad_r + b2_ad (preR for ad2)
    k_pre<HID, true><<<gN, blk, 0, stream>>>(B, w2_tx_l, nullptr, B,
                                             w2_ad_r, b2_ad, D, NADDR);
    // ---- layer 2 aggregations ----
    k_agg<false><<<gG, blk, 0, stream>>>(rp_tx, col_at, B, C, C, nullptr, nullptr, NTX);   // C = tx2
    k_agg<false><<<gG, blk, 0, stream>>>(rp_ad, col_ta, A, D, D, nullptr, nullptr, NADDR); // D = ad2

    // ---- layer 3 pre-transforms ----
    k_pre<HID, false><<<gN, blk, 0, stream>>>(C, w3_ad_l, nullptr, A,
                                              nullptr, nullptr, nullptr, NTX);   // A = preL
    k_pre<HID, false><<<gN, blk, 0, stream>>>(D, w3_ad_r, b3_ad, B,
                                              nullptr, nullptr, nullptr, NADDR); // B = preR
    // ---- layer 3 aggregation + classifier ----
    k_agg<true><<<gG, blk, 0, stream>>>(rp_ad, col_ta, A, B, out, w_out, b_out, NADDR);
}

// Round 8
// 659.483 us; speedup vs baseline: 2.5957x; 1.1611x over previous
//
#include <hip/hip_runtime.h>

#define NADDR 400000
#define NTX   400000
#define NEDGE 1500000
#define FIN   64
#define HID   32
#define NB    1563        // buckets per node type; 256 nodes per bucket
#define LSTR  36          // LDS row stride (floats): 144 B, 16B-aligned rows

static inline int cdiv_host(long a, int b) { return (int)((a + b - 1) / b); }

// ================= bucketed CSR build (verified round-4 chain) ==============

__global__ void k_hist(const int* __restrict__ at_dst, const int* __restrict__ ta_dst,
                       int* __restrict__ bcnt /*[2*NB]*/, int GH) {
    __shared__ int h[NB];
    bool wh = blockIdx.x >= GH;
    int blk = blockIdx.x - (wh ? GH : 0);
    const int* dst = wh ? ta_dst : at_dst;
    for (int i = threadIdx.x; i < NB; i += 256) h[i] = 0;
    __syncthreads();
    for (long e = (long)blk * 256 + threadIdx.x; e < NEDGE; e += (long)GH * 256)
        atomicAdd(&h[dst[e] >> 8], 1);
    __syncthreads();
    int* g = bcnt + (wh ? NB : 0);
    for (int i = threadIdx.x; i < NB; i += 256) {
        int v = h[i];
        if (v) atomicAdd(&g[i], v);
    }
}

__global__ void k_scan_nb(const int* __restrict__ bcnt, int* __restrict__ bbase,
                          int* __restrict__ gcur) {
    __shared__ int sm[256];
    __shared__ int carry;
    int w = blockIdx.x;
    int t = threadIdx.x;
    if (t == 0) carry = 0;
    __syncthreads();
    for (int base = 0; base < NB; base += 256) {
        int i = base + t;
        int v = (i < NB) ? bcnt[w * NB + i] : 0;
        sm[t] = v;
        __syncthreads();
        for (int off = 1; off < 256; off <<= 1) {
            int x = (t >= off) ? sm[t - off] : 0;
            __syncthreads();
            sm[t] += x;
            __syncthreads();
        }
        int excl = sm[t] - v + carry;
        if (i < NB) { bbase[w * (NB + 1) + i] = excl; gcur[w * NB + i] = excl; }
        int tot = sm[255];
        __syncthreads();
        if (t == 0) carry += tot;
        __syncthreads();
    }
    if (t == 0) bbase[w * (NB + 1) + NB] = NEDGE;
}

__global__ void k_dist(const int* __restrict__ ei_at, const int* __restrict__ ei_ta,
                       int* __restrict__ gcur, unsigned* __restrict__ eb_at,
                       unsigned* __restrict__ eb_ta, int GD) {
    __shared__ int h[NB];
    __shared__ int bs[NB];
    bool wh = blockIdx.x >= GD;
    int blk = blockIdx.x - (wh ? GD : 0);
    const int* ei = wh ? ei_ta : ei_at;
    unsigned* eb = wh ? eb_ta : eb_at;
    for (int i = threadIdx.x; i < NB; i += 256) h[i] = 0;
    __syncthreads();
    long e0 = (long)blk * 256 + threadIdx.x;
    long stride = (long)GD * 256;
    for (long e = e0; e < NEDGE; e += stride)
        atomicAdd(&h[ei[NEDGE + e] >> 8], 1);
    __syncthreads();
    int* gc = gcur + (wh ? NB : 0);
    for (int i = threadIdx.x; i < NB; i += 256) {
        int c = h[i];
        bs[i] = c ? atomicAdd(&gc[i], c) : 0;
        h[i] = 0;
    }
    __syncthreads();
    for (long e = e0; e < NEDGE; e += stride) {
        int d = ei[NEDGE + e];
        int s = ei[e];
        int b = d >> 8;
        int r = atomicAdd(&h[b], 1);
        eb[bs[b] + r] = ((unsigned)s << 8) | (unsigned)(d & 255);
    }
}

__global__ void k_csrb(const unsigned* __restrict__ eb_at, const unsigned* __restrict__ eb_ta,
                       const int* __restrict__ bbase,
                       int* __restrict__ rp_tx, int* __restrict__ rp_ad,
                       int* __restrict__ col_at, int* __restrict__ col_ta) {
    __shared__ int deg[256];
    __shared__ int cur[256];
    __shared__ int sm[256];
    bool wh = blockIdx.x >= NB;
    int b = blockIdx.x - (wh ? NB : 0);
    const unsigned* eb = wh ? eb_ta : eb_at;
    int* rp  = wh ? rp_ad  : rp_tx;
    int* col = wh ? col_ta : col_at;
    const int* bb = bbase + (wh ? (NB + 1) : 0);
    int e0 = bb[b], e1 = bb[b + 1];
    int t = threadIdx.x;
    deg[t] = 0;
    __syncthreads();
    for (int e = e0 + t; e < e1; e += 256)
        atomicAdd(&deg[eb[e] & 255], 1);
    __syncthreads();
    int v = deg[t];
    sm[t] = v;
    __syncthreads();
    for (int off = 1; off < 256; off <<= 1) {
        int x = (t >= off) ? sm[t - off] : 0;
        __syncthreads();
        sm[t] += x;
        __syncthreads();
    }
    int excl = sm[t] - v;
    int node = b * 256 + t;
    if (node < 400000) rp[node] = e0 + excl;
    cur[t] = e0 + excl;
    __syncthreads();
    for (int e = e0 + t; e < e1; e += 256) {
        unsigned p = eb[e];
        int idx = atomicAdd(&cur[p & 255], 1);
        col[idx] = (int)(p >> 8);
    }
    if (t == 0 && b == 0) rp[400000] = NEDGE;
}

// ================= LDS-tiled dense pre-transforms ===========================
// Block = 256 threads = 256 rows. K-tiles of 32 feats staged in LDS with
// fully coalesced global loads; compute preloads the thread's row into
// registers (8 x ds_read_b128) then runs a fully-unrolled FMA block whose
// only memory dependency is the wave-uniform (scalar-cached) weight stream.
// Outputs staged back through LDS for full-line coalesced stores (no RFO).
// outa may alias x: block reads only its own rows; barrier before stores.
template<int F, bool DUAL>
__global__ __launch_bounds__(256)
void k_pre(const float* __restrict__ x,
           const float* __restrict__ wa, const float* __restrict__ ba,
           float* __restrict__ outa,
           const float* __restrict__ wb, const float* __restrict__ bb,
           float* __restrict__ outb, int n) {
    __shared__ alignas(16) float xs[256 * LSTR];
    int t = threadIdx.x;
    long row0 = (long)blockIdx.x * 256;

    float aa[HID], ab[DUAL ? HID : 1];
#pragma unroll
    for (int j = 0; j < HID; ++j) aa[j] = ba ? ba[j] : 0.0f;
    if (DUAL) {
#pragma unroll
        for (int j = 0; j < HID; ++j) ab[j] = bb[j];
    }

    for (int kt = 0; kt < F / 32; ++kt) {
        // ---- stage K-tile [256 rows x 32 feats], coalesced ----
#pragma unroll
        for (int sub = 0; sub < 8; ++sub) {
            int f = sub * 256 + t;          // float4 slot in tile
            int r = f >> 3, k4 = f & 7;
            long gr = row0 + r;
            if (gr >= n) gr = n - 1;
            float4 v = *(const float4*)(x + gr * F + kt * 32 + k4 * 4);
            *(float4*)(&xs[r * LSTR + k4 * 4]) = v;
        }
        __syncthreads();
        // ---- preload this thread's row into registers (independent b128s) --
        float xr[32];
#pragma unroll
        for (int q = 0; q < 8; ++q) {
            float4 v = *(const float4*)(&xs[t * LSTR + q * 4]);
            xr[q * 4 + 0] = v.x; xr[q * 4 + 1] = v.y;
            xr[q * 4 + 2] = v.z; xr[q * 4 + 3] = v.w;
        }
        // ---- fully-unrolled FMA blocks ----
        const float* wka = wa + kt * 32 * HID;
#pragma unroll
        for (int k = 0; k < 32; ++k) {
            float xk = xr[k];
            const float* wr = wka + k * HID;
#pragma unroll
            for (int j = 0; j < HID; ++j) aa[j] = __builtin_fmaf(xk, wr[j], aa[j]);
        }
        if (DUAL) {
            const float* wkb = wb + kt * 32 * HID;
#pragma unroll
            for (int k = 0; k < 32; ++k) {
                float xk = xr[k];
                const float* wr = wkb + k * HID;
#pragma unroll
                for (int j = 0; j < HID; ++j) ab[j] = __builtin_fmaf(xk, wr[j], ab[j]);
            }
        }
        __syncthreads();
    }

    // ---- store outa via LDS, full-line coalesced ----
#pragma unroll
    for (int j = 0; j < HID; j += 4)
        *(float4*)(&xs[t * LSTR + j]) = make_float4(aa[j], aa[j + 1], aa[j + 2], aa[j + 3]);
    __syncthreads();
#pragma unroll
    for (int sub = 0; sub < 8; ++sub) {
        int f = sub * 256 + t;
        int r = f >> 3, k4 = f & 7;
        long gr = row0 + r;
        if (gr < n) {
            float4 v = *(const float4*)(&xs[r * LSTR + k4 * 4]);
            *(float4*)(outa + gr * HID + k4 * 4) = v;
        }
    }
    if (DUAL) {
        __syncthreads();
#pragma unroll
        for (int j = 0; j < HID; j += 4)
            *(float4*)(&xs[t * LSTR + j]) = make_float4(ab[j], ab[j + 1], ab[j + 2], ab[j + 3]);
        __syncthreads();
#pragma unroll
        for (int sub = 0; sub < 8; ++sub) {
            int f = sub * 256 + t;
            int r = f >> 3, k4 = f & 7;
            long gr = row0 + r;
            if (gr < n) {
                float4 v = *(const float4*)(&xs[r * LSTR + k4 * 4]);
                *(float4*)(outb + gr * HID + k4 * 4) = v;
            }
        }
    }
}

// ================= shuffle-free SAGE aggregation ============================
template<bool FINAL>
__global__ __launch_bounds__(256)
void k_agg(const int* __restrict__ rp, const int* __restrict__ col,
           const float* __restrict__ preL, const float* __restrict__ preR,
           float* __restrict__ y,
           const float* __restrict__ wo, const float* __restrict__ bo, int n) {
    int t = blockIdx.x * 256 + threadIdx.x;
    int g = t >> 3;     // node
    int u = t & 7;      // float4 slot within row
    if (g >= n) return;
    int p0 = rp[g], p1 = rp[g + 1];

    float ax = 0.0f, ay = 0.0f, az = 0.0f, aw = 0.0f;
    for (int k = p0; k < p1; k += 8) {
        int last = p1 - 1;
        int idx[8];
#pragma unroll
        for (int q = 0; q < 8; ++q) {
            int e = k + q;
            idx[q] = col[e < p1 ? e : last];
        }
        float4 v[8];
#pragma unroll
        for (int q = 0; q < 8; ++q)
            v[q] = *(const float4*)(preL + (size_t)idx[q] * HID + u * 4);
#pragma unroll
        for (int q = 0; q < 8; ++q) {
            if (k + q < p1) {
                ax += v[q].x; ay += v[q].y; az += v[q].z; aw += v[q].w;
            }
        }
    }
    float inv = 1.0f / fmaxf((float)(p1 - p0), 1.0f);
    float4 r = *(const float4*)(preR + (size_t)g * HID + u * 4);
    float4 h;
    h.x = fmaxf(__builtin_fmaf(ax, inv, r.x), 0.0f);
    h.y = fmaxf(__builtin_fmaf(ay, inv, r.y), 0.0f);
    h.z = fmaxf(__builtin_fmaf(az, inv, r.z), 0.0f);
    h.w = fmaxf(__builtin_fmaf(aw, inv, r.w), 0.0f);

    if (!FINAL) {
        *(float4*)(y + (size_t)g * HID + u * 4) = h;
    } else {
        int j = u * 4;
        float o0 = h.x * wo[(j + 0) * 2 + 0] + h.y * wo[(j + 1) * 2 + 0]
                 + h.z * wo[(j + 2) * 2 + 0] + h.w * wo[(j + 3) * 2 + 0];
        float o1 = h.x * wo[(j + 0) * 2 + 1] + h.y * wo[(j + 1) * 2 + 1]
                 + h.z * wo[(j + 2) * 2 + 1] + h.w * wo[(j + 3) * 2 + 1];
#pragma unroll
        for (int m = 4; m >= 1; m >>= 1) {
            o0 += __shfl_xor(o0, m, 8);
            o1 += __shfl_xor(o1, m, 8);
        }
        if (u == 0) {
            y[(size_t)g * 2 + 0] = o0 + bo[0];
            y[(size_t)g * 2 + 1] = o1 + bo[1];
        }
    }
}

// ============================================================================

extern "C" void kernel_launch(void* const* d_in, const int* in_sizes, int n_in,
                              void* d_out, int out_size, void* d_ws, size_t ws_size,
                              hipStream_t stream) {
    const float* x_addr  = (const float*)d_in[0];
    const float* x_tx    = (const float*)d_in[1];
    const int*   ei_at   = (const int*)d_in[2];
    const int*   ei_ta   = (const int*)d_in[3];
    const float* w1_tx_l = (const float*)d_in[4];  const float* b1_tx = (const float*)d_in[5];
    const float* w1_tx_r = (const float*)d_in[6];
    const float* w1_ad_l = (const float*)d_in[7];  const float* b1_ad = (const float*)d_in[8];
    const float* w1_ad_r = (const float*)d_in[9];
    const float* w2_tx_l = (const float*)d_in[10]; const float* b2_tx = (const float*)d_in[11];
    const float* w2_tx_r = (const float*)d_in[12];
    const float* w2_ad_l = (const float*)d_in[13]; const float* b2_ad = (const float*)d_in[14];
    const float* w2_ad_r = (const float*)d_in[15];
    // d_in[16..18] unused (w3_tx_*)
    const float* w3_ad_l = (const float*)d_in[19]; const float* b3_ad = (const float*)d_in[20];
    const float* w3_ad_r = (const float*)d_in[21];
    const float* w_out   = (const float*)d_in[22]; const float* b_out = (const float*)d_in[23];
    float* out = (float*)d_out;

    // ---- workspace carve ----
    char* base = (char*)d_ws;
    int* bcnt   = (int*)base;  base += (size_t)(2 * NB) * 4;
    int* bbase  = (int*)base;  base += (size_t)(2 * (NB + 1)) * 4;
    int* gcur   = (int*)base;  base += (size_t)(2 * NB) * 4;
    int* rp_tx  = (int*)base;  base += (size_t)(NTX + 1) * 4;
    int* rp_ad  = (int*)base;  base += (size_t)(NADDR + 1) * 4;
    int* col_at = (int*)base;  base += (size_t)NEDGE * 4;
    int* col_ta = (int*)base;  base += (size_t)NEDGE * 4;
    unsigned* eb_at = (unsigned*)base;  base += (size_t)NEDGE * 4;
    unsigned* eb_ta = (unsigned*)base;  base += (size_t)NEDGE * 4;
    base = (char*)(((size_t)base + 255) & ~(size_t)255);
    const size_t SLOT = (size_t)400000 * HID;
    float* A = (float*)base;
    float* B = A + SLOT;
    float* C = B + SLOT;
    float* D = C + SLOT;

    dim3 blk(256);
    int gN = cdiv_host(400000, 256);              // 1563
    int gG = cdiv_host((long)400000 * 8, 256);    // 12500
    const int GH = 96, GD = 192;

    // ---- bucketed CSR build ----
    hipMemsetAsync(bcnt, 0, (size_t)(2 * NB) * 4, stream);
    k_hist<<<2 * GH, blk, 0, stream>>>(ei_at + NEDGE, ei_ta + NEDGE, bcnt, GH);
    k_scan_nb<<<2, blk, 0, stream>>>(bcnt, bbase, gcur);
    k_dist<<<2 * GD, blk, 0, stream>>>(ei_at, ei_ta, gcur, eb_at, eb_ta, GD);
    k_csrb<<<2 * NB, blk, 0, stream>>>(eb_at, eb_ta, bbase, rp_tx, rp_ad, col_at, col_ta);

    // ---- layer 1 pre-transforms ----
    // A = x_addr@w1_tx_l (preL for tx)       B = x_addr@w1_ad_r + b1_ad (preR for ad)
    k_pre<FIN, true><<<gN, blk, 0, stream>>>(x_addr, w1_tx_l, nullptr, A,
                                             w1_ad_r, b1_ad, B, NADDR);
    // C = x_tx@w1_ad_l (preL for ad)         D = x_tx@w1_tx_r + b1_tx (preR for tx)
    k_pre<FIN, true><<<gN, blk, 0, stream>>>(x_tx, w1_ad_l, nullptr, C,
                                             w1_tx_r, b1_tx, D, NTX);
    // ---- layer 1 aggregations ----
    k_agg<false><<<gG, blk, 0, stream>>>(rp_tx, col_at, A, D, D, nullptr, nullptr, NTX);   // D = tx
    k_agg<false><<<gG, blk, 0, stream>>>(rp_ad, col_ta, C, B, B, nullptr, nullptr, NADDR); // B = ad

    // ---- layer 2 pre-transforms ----
    // A = tx@w2_ad_l (preL for ad2)          C = tx@w2_tx_r + b2_tx (preR for tx2)
    k_pre<HID, true><<<gN, blk, 0, stream>>>(D, w2_ad_l, nullptr, A,
                                             w2_tx_r, b2_tx, C, NTX);
    // B = ad@w2_tx_l in-place (preL for tx2) D = ad@w2_ad_r + b2_ad (preR for ad2)
    k_pre<HID, true><<<gN, blk, 0, stream>>>(B, w2_tx_l, nullptr, B,
                                             w2_ad_r, b2_ad, D, NADDR);
    // ---- layer 2 aggregations ----
    k_agg<false><<<gG, blk, 0, stream>>>(rp_tx, col_at, B, C, C, nullptr, nullptr, NTX);   // C = tx2
    k_agg<false><<<gG, blk, 0, stream>>>(rp_ad, col_ta, A, D, D, nullptr, nullptr, NADDR); // D = ad2

    // ---- layer 3 pre-transforms ----
    k_pre<HID, false><<<gN, blk, 0, stream>>>(C, w3_ad_l, nullptr, A,
                                              nullptr, nullptr, nullptr, NTX);   // A = preL
    k_pre<HID, false><<<gN, blk, 0, stream>>>(D, w3_ad_r, b3_ad, B,
                                              nullptr, nullptr, nullptr, NADDR); // B = preR
    // ---- layer 3 aggregation + classifier ----
    k_agg<true><<<gG, blk, 0, stream>>>(rp_ad, col_ta, A, B, out, w_out, b_out, NADDR);
}